// Round 12
// baseline (354.158 us; speedup 1.0000x reference)
//
#include <hip/hip_runtime.h>
#include <hip/hip_bf16.h>
#include <stdint.h>

#define G_    1024
#define NPG   64
#define EPG   256
#define N_    (G_*NPG)     // 65536
#define E_    (G_*EPG)     // 262144
#define IN_CH 768
#define CH    128
#define KSEL  128
#define HID   512          // 4*CH

// ---- output layout (element offsets, all float32) ----
#define NCH  (N_*CH)       // 8388608
#define GK   (G_*KSEL)     // 131072
#define OFF0 0
#define OFF1 (OFF0 + NCH)
#define OFF2 (OFF1 + 2*GK)
#define OFF3 (OFF2 + GK)
#define OFF4 (OFF3 + GK)
#define OFF5 (OFF4 + N_)
#define OFF6 (OFF5 + NCH)
#define OFF7 (OFF6 + 2*GK)
#define OFF8 (OFF7 + GK)
#define OFF9 (OFF8 + GK)
#define OFF10 (OFF9 + N_)

typedef unsigned short u16;
typedef unsigned int   u32;
typedef __attribute__((ext_vector_type(8))) short bf16x8;
typedef __attribute__((ext_vector_type(4))) float f32x4;

__device__ __forceinline__ u16 f2bf(float x) {
    union { float f; u32 u; } v; v.f = x;
    u32 r = v.u + 0x7fffu + ((v.u >> 16) & 1u);   // RNE
    return (u16)(r >> 16);
}
__device__ __forceinline__ float bf2f(u32 h) {
    union { u32 u; float f; } v; v.u = h << 16; return v.f;
}
__device__ __forceinline__ u16 bfc(float x) {
    __hip_bfloat16 h = __float2bfloat16(x);
    return *reinterpret_cast<u16*>(&h);
}

__global__ void k_deg(const int* __restrict__ ei, const float* __restrict__ ea,
                      float* __restrict__ deg) {
    int e = blockIdx.x * 256 + threadIdx.x;
    if (e < E_) atomicAdd(&deg[ei[E_ + e]], ea[e]);
}

__global__ void k_dis(float* __restrict__ deg) {
    int i = blockIdx.x * 256 + threadIdx.x;
    if (i < N_) { float d = deg[i]; deg[i] = d > 0.f ? 1.0f / sqrtf(d) : 0.f; }
}

__global__ void k_norm(const int* __restrict__ ei, const float* __restrict__ ea,
                       const float* __restrict__ dis, float* __restrict__ norm) {
    int e = blockIdx.x * 256 + threadIdx.x;
    if (e < E_) norm[e] = dis[ei[e]] * ea[e] * dis[ei[E_ + e]];
}

// Build TRANSPOSED bf16 weights (row = output col, cols = K).
__global__ void k_concat(const float* __restrict__ W1, const float* __restrict__ V1,
                         const float* __restrict__ W2, const float* __restrict__ V2,
                         const float* __restrict__ mw1,
                         u16* __restrict__ WV1t, u16* __restrict__ WV2t,
                         u16* __restrict__ Mwt) {
    int i = blockIdx.x * 256 + threadIdx.x;
    if (i < 256 * IN_CH) {
        int c = i / IN_CH, r = i - c * IN_CH;
        WV1t[i] = f2bf(c < CH ? W1[r*CH + c] : V1[r*CH + (c - CH)]);
    }
    if (i < 256 * CH) {
        int c = i >> 7, r = i & 127;
        WV2t[i] = f2bf(c < CH ? W2[r*CH + c] : V2[r*CH + (c - CH)]);
    }
    if (i < 1024 * CH) {
        int c = i >> 7, r = i & 127;
        Mwt[i] = f2bf(c < HID ? mw1[r*HID + c] : mw1[(CH + r)*HID + (c - HID)]);
    }
}

// Layer-1 GEMM: C(N x 256 bf16) = bf16(x(N x 768 f32)) @ WV1t^T.
// BM=16, FULL-K panel in LDS: one dense LINEAR 48 KB stage burst per block
// (the access pattern that measures 7+ TB/s), ONE barrier, then 24 K-steps
// from LDS + L2-resident B with no further barriers or global A traffic.
// 48 KB LDS -> 3 blocks/CU: stage bursts overlap neighbors' compute.
// Swizzle: XOR 16B-slot within each 128B window by row&7 on the global
// SOURCE (same lines touched -> still linear); inverse on ds_read.
__global__ __launch_bounds__(256) void k_gemm1(const float* __restrict__ Ap,
        const u16* __restrict__ Bt, u16* __restrict__ Cp) {
    __shared__ float As[16 * 768];        // 48 KB
    const int t = threadIdx.x;
    const int lane = t & 63, w = t >> 6;
    const int wc = w * 64;                // wave's 64 output cols
    const size_t bm = (size_t)blockIdx.x * 16;
    const int r16 = lane & 15, kq = lane >> 4;

    // ---- stage: 3072 granules (16B), 12 per thread, linear LDS dest ----
    #pragma unroll
    for (int i = 0; i < 12; ++i) {
        int g = i * 256 + t;                  // linear granule index
        int row = g / 192;                    // 192 granules per 3072B row
        int slot = g & 7;
        int gsrc = (g & ~7) | (slot ^ (row & 7));   // inverse-swizzled source
        const float* src = Ap + bm * IN_CH + (size_t)gsrc * 4;
        __builtin_amdgcn_global_load_lds(
            (const __attribute__((address_space(1))) void*)src,
            (__attribute__((address_space(3))) void*)&As[g * 4],
            16, 0, 0);
    }
    __syncthreads();     // the ONLY barrier (vmcnt(0)+lgkmcnt(0)+s_barrier)

    f32x4 acc[4];
    #pragma unroll
    for (int n = 0; n < 4; ++n) acc[n] = (f32x4){0.f, 0.f, 0.f, 0.f};

    const int xr = r16 & 7;
    #pragma unroll 4
    for (int ki = 0; ki < 24; ++ki) {
        // A fragment: row r16, k-floats [32ki + 8kq, +8): two swizzled granules
        const float* rowbase = &As[r16 * IN_CH + ki * 32];
        float4 q0 = *(const float4*)(rowbase + (((2 * kq)     ^ xr) * 4));
        float4 q1 = *(const float4*)(rowbase + (((2 * kq + 1) ^ xr) * 4));
        union { bf16x8 v; u16 s[8]; } pk;
        pk.s[0] = bfc(q0.x); pk.s[1] = bfc(q0.y); pk.s[2] = bfc(q0.z); pk.s[3] = bfc(q0.w);
        pk.s[4] = bfc(q1.x); pk.s[5] = bfc(q1.y); pk.s[6] = bfc(q1.z); pk.s[7] = bfc(q1.w);
        bf16x8 a = pk.v;
        #pragma unroll
        for (int n = 0; n < 4; ++n) {
            bf16x8 b = *(const bf16x8*)(Bt + (wc + n * 16 + r16) * (size_t)IN_CH + ki * 32 + kq * 8);
            acc[n] = __builtin_amdgcn_mfma_f32_16x16x32_bf16(a, b, acc[n], 0, 0, 0);
        }
    }

    // C/D: col = lane&15, row = (lane>>4)*4 + reg  (single 16-row m-frag)
    #pragma unroll
    for (int j = 0; j < 4; ++j) {
        size_t row = bm + kq * 4 + j;
        #pragma unroll
        for (int n = 0; n < 4; ++n) {
            size_t col = wc + n * 16 + r16;
            Cp[row * 256 + col] = f2bf(acc[n][j]);
        }
    }
}

// Layer-1 aggregation + epilogue (B bf16 [N][256] = [m|v]).
__global__ __launch_bounds__(256) void k_agg1(const int* __restrict__ ei,
        const float* __restrict__ norm, const u16* __restrict__ Bb,
        const float* __restrict__ bias, u16* __restrict__ x1b) {
    __shared__ float A_s[64 * 65];
    __shared__ u16   Ms[64 * 132];
    const int g = blockIdx.x, t = threadIdx.x;
    const int lane = t & 63, w = t >> 6;
    const int r16 = lane & 15, kq = lane >> 4;
    const size_t nbase = (size_t)g * 64;

    for (int i = t; i < 64 * 65; i += 256) A_s[i] = 0.f;
    for (int i = t; i < 64 * 32; i += 256) {
        int row = i >> 5, c4 = (i & 31) << 2;
        *(uint2*)&Ms[row * 132 + c4] = *(const uint2*)(Bb + (nbase + row) * 256 + c4);
    }
    __syncthreads();
    { int e = g * 256 + t;
      atomicAdd(&A_s[(ei[e] & 63) * 65 + (ei[E_ + e] & 63)], norm[e]); }
    __syncthreads();

    const int n0 = w * 32;
    f32x4 acc[4][2];
    #pragma unroll
    for (int mt = 0; mt < 4; ++mt)
        #pragma unroll
        for (int nt = 0; nt < 2; ++nt)
            acc[mt][nt] = (f32x4){0.f, 0.f, 0.f, 0.f};

    union bfr { bf16x8 v; u16 s[8]; };
    #pragma unroll
    for (int ks = 0; ks < 2; ++ks) {
        bfr a[4], b[2];
        #pragma unroll
        for (int mt = 0; mt < 4; ++mt)
            #pragma unroll
            for (int i = 0; i < 8; ++i)
                a[mt].s[i] = f2bf(A_s[(ks*32 + kq*8 + i) * 65 + mt*16 + r16]);
        #pragma unroll
        for (int nt = 0; nt < 2; ++nt)
            #pragma unroll
            for (int i = 0; i < 8; ++i)
                b[nt].s[i] = Ms[(ks*32 + kq*8 + i) * 132 + n0 + nt*16 + r16];
        #pragma unroll
        for (int mt = 0; mt < 4; ++mt)
            #pragma unroll
            for (int nt = 0; nt < 2; ++nt)
                acc[mt][nt] = __builtin_amdgcn_mfma_f32_16x16x32_bf16(a[mt].v, b[nt].v, acc[mt][nt], 0, 0, 0);
    }
    #pragma unroll
    for (int mt = 0; mt < 4; ++mt)
        #pragma unroll
        for (int j = 0; j < 4; ++j) {
            int c = mt * 16 + kq * 4 + j;
            size_t node = nbase + c;
            #pragma unroll
            for (int nt = 0; nt < 2; ++nt) {
                int ch = n0 + nt * 16 + r16;
                float v = bf2f(Bb[node * 256 + 128 + ch]) + bias[ch];
                x1b[node * 128 + ch] = f2bf(fmaxf(acc[mt][nt][j] + v, 0.f));
            }
        }
}

// Fused layer-2: per-graph GEMM (mv = x1g @ WV2t^T, 64x256) into LDS,
// then dense-adjacency aggregation + epilogue.
__global__ __launch_bounds__(256) void k_l2agg(const u16* __restrict__ x1b,
        const u16* __restrict__ Wt, const int* __restrict__ ei,
        const float* __restrict__ norm, const float* __restrict__ bias,
        float* __restrict__ out0, float* __restrict__ out5,
        u16* __restrict__ xb) {
    __shared__ float A_s[64 * 65];
    __shared__ u16   MVs[64 * 264];
    const int g = blockIdx.x, t = threadIdx.x;
    const int lane = t & 63, w = t >> 6;
    const int r16 = lane & 15, kq = lane >> 4;
    const size_t nbase = (size_t)g * 64;

    for (int i = t; i < 64 * 65; i += 256) A_s[i] = 0.f;
    __syncthreads();
    { int e = g * 256 + t;
      atomicAdd(&A_s[(ei[e] & 63) * 65 + (ei[E_ + e] & 63)], norm[e]); }

    const int wc = w * 64;
    f32x4 acc[4][4];
    #pragma unroll
    for (int mt = 0; mt < 4; ++mt)
        #pragma unroll
        for (int n = 0; n < 4; ++n)
            acc[mt][n] = (f32x4){0.f, 0.f, 0.f, 0.f};
    #pragma unroll
    for (int ks = 0; ks < 4; ++ks) {
        int k0 = ks * 32;
        bf16x8 a[4], b[4];
        #pragma unroll
        for (int mt = 0; mt < 4; ++mt)
            a[mt] = *(const bf16x8*)(x1b + (nbase + mt * 16 + r16) * 128 + k0 + kq * 8);
        #pragma unroll
        for (int n = 0; n < 4; ++n)
            b[n] = *(const bf16x8*)(Wt + (size_t)(wc + n * 16 + r16) * 128 + k0 + kq * 8);
        #pragma unroll
        for (int mt = 0; mt < 4; ++mt)
            #pragma unroll
            for (int n = 0; n < 4; ++n)
                acc[mt][n] = __builtin_amdgcn_mfma_f32_16x16x32_bf16(a[mt], b[n], acc[mt][n], 0, 0, 0);
    }
    #pragma unroll
    for (int mt = 0; mt < 4; ++mt)
        #pragma unroll
        for (int j = 0; j < 4; ++j) {
            int row = mt * 16 + kq * 4 + j;
            #pragma unroll
            for (int n = 0; n < 4; ++n)
                MVs[row * 264 + wc + n * 16 + r16] = f2bf(acc[mt][n][j]);
        }
    __syncthreads();

    const int n0 = w * 32;
    f32x4 ag[4][2];
    #pragma unroll
    for (int mt = 0; mt < 4; ++mt)
        #pragma unroll
        for (int nt = 0; nt < 2; ++nt)
            ag[mt][nt] = (f32x4){0.f, 0.f, 0.f, 0.f};
    union bfr { bf16x8 v; u16 s[8]; };
    #pragma unroll
    for (int ks = 0; ks < 2; ++ks) {
        bfr a[4], b[2];
        #pragma unroll
        for (int mt = 0; mt < 4; ++mt)
            #pragma unroll
            for (int i = 0; i < 8; ++i)
                a[mt].s[i] = f2bf(A_s[(ks*32 + kq*8 + i) * 65 + mt*16 + r16]);
        #pragma unroll
        for (int nt = 0; nt < 2; ++nt)
            #pragma unroll
            for (int i = 0; i < 8; ++i)
                b[nt].s[i] = MVs[(ks*32 + kq*8 + i) * 264 + n0 + nt*16 + r16];
        #pragma unroll
        for (int mt = 0; mt < 4; ++mt)
            #pragma unroll
            for (int nt = 0; nt < 2; ++nt)
                ag[mt][nt] = __builtin_amdgcn_mfma_f32_16x16x32_bf16(a[mt].v, b[nt].v, ag[mt][nt], 0, 0, 0);
    }
    #pragma unroll
    for (int mt = 0; mt < 4; ++mt)
        #pragma unroll
        for (int j = 0; j < 4; ++j) {
            int c = mt * 16 + kq * 4 + j;
            size_t node = nbase + c;
            #pragma unroll
            for (int nt = 0; nt < 2; ++nt) {
                int ch = n0 + nt * 16 + r16;
                float v = bf2f(MVs[c * 264 + 128 + ch]) + bias[ch];
                float r = fmaxf(ag[mt][nt][j] + v, 0.f);
                out0[node * 128 + ch] = r;
                out5[node * 128 + ch] = r;
                xb[node * 128 + ch] = f2bf(r);
            }
        }
}

// Fused GEMM3 + edge MLP, one block per graph, 512 threads = 8 waves.
#define PQS 1032
__global__ __launch_bounds__(512) void k_pqedge(const u16* __restrict__ x2b,
        const u16* __restrict__ Mwt, const int* __restrict__ ei,
        const float* __restrict__ mb1, const float* __restrict__ mw2,
        const float* __restrict__ mb2, float* __restrict__ pred) {
    __shared__ u16 PQs[64 * PQS];
    __shared__ float mw2s[512];
    const int g = blockIdx.x, t = threadIdx.x;
    const int lane = t & 63, w = t >> 6;
    const int r16 = lane & 15, kq = lane >> 4;
    const int nb = w * 128;

    if (t < 128) *(float4*)&mw2s[t * 4] = *(const float4*)&mw2[t * 4];

    f32x4 acc[4][8];
    #pragma unroll
    for (int mt = 0; mt < 4; ++mt)
        #pragma unroll
        for (int nt = 0; nt < 8; ++nt)
            acc[mt][nt] = (f32x4){0.f, 0.f, 0.f, 0.f};

    #pragma unroll
    for (int ks = 0; ks < 4; ++ks) {
        const int k0 = ks * 32;
        bf16x8 a[4], b[8];
        #pragma unroll
        for (int mt = 0; mt < 4; ++mt)
            a[mt] = *(const bf16x8*)(x2b + ((size_t)g * 64 + mt * 16 + r16) * 128 + k0 + kq * 8);
        #pragma unroll
        for (int nt = 0; nt < 8; ++nt)
            b[nt] = *(const bf16x8*)(Mwt + (size_t)(nb + nt * 16 + r16) * 128 + k0 + kq * 8);
        #pragma unroll
        for (int mt = 0; mt < 4; ++mt)
            #pragma unroll
            for (int nt = 0; nt < 8; ++nt)
                acc[mt][nt] = __builtin_amdgcn_mfma_f32_16x16x32_bf16(a[mt], b[nt], acc[mt][nt], 0, 0, 0);
    }
    #pragma unroll
    for (int nt = 0; nt < 8; ++nt) {
        int col = nb + nt * 16 + r16;
        float bias = (col < HID) ? mb1[col] : 0.f;
        #pragma unroll
        for (int mt = 0; mt < 4; ++mt)
            #pragma unroll
            for (int j = 0; j < 4; ++j) {
                int row = mt * 16 + kq * 4 + j;
                PQs[row * PQS + col] = f2bf(acc[mt][nt][j] + bias);
            }
    }
    __syncthreads();

    const int le = lane & 31, jh = lane >> 5;
    const int e = g * 256 + w * 32 + le;
    const int r = ei[e] & 63, c = ei[E_ + e] & 63;
    const u16* pP = &PQs[r * PQS + jh * 256];
    const u16* pQ = &PQs[c * PQS + 512 + jh * 256];
    const float* pW = &mw2s[jh * 256];
    float s = 0.f;
    #pragma unroll 8
    for (int it = 0; it < 32; ++it) {
        uint4 up = *(const uint4*)(pP + it * 8);
        uint4 uq = *(const uint4*)(pQ + it * 8);
        float4 w0 = *(const float4*)(pW + it * 8);
        float4 w1 = *(const float4*)(pW + it * 8 + 4);
        u32 pu[4] = {up.x, up.y, up.z, up.w};
        u32 qu[4] = {uq.x, uq.y, uq.z, uq.w};
        float ww[8] = {w0.x,w0.y,w0.z,w0.w,w1.x,w1.y,w1.z,w1.w};
        #pragma unroll
        for (int k = 0; k < 4; ++k) {
            float p0 = bf2f(pu[k] & 0xffffu), p1 = bf2f(pu[k] >> 16);
            float q0 = bf2f(qu[k] & 0xffffu), q1 = bf2f(qu[k] >> 16);
            s += fmaxf(p0 + q0, 0.f) * ww[2*k];
            s += fmaxf(p1 + q1, 0.f) * ww[2*k + 1];
        }
    }
    s += __shfl_xor(s, 32, 64);
    if (lane < 32) pred[e] = s + mb2[0];
}

// one block per graph: stable bitonic sort (desc by pred, ties by idx asc)
__global__ __launch_bounds__(256) void k_sort(const float* __restrict__ pred,
        const int* __restrict__ ei, const float* __restrict__ ea,
        float* __restrict__ out) {
    __shared__ float key[256];
    __shared__ int   idx[256];
    int g = blockIdx.x, t = threadIdx.x;
    int ebase = g * EPG;
    float p = pred[ebase + t];
    key[t] = p; idx[t] = t;
    for (int k2 = 2; k2 <= 256; k2 <<= 1) {
        for (int j = k2 >> 1; j >= 1; j >>= 1) {
            __syncthreads();
            int ixj = t ^ j;
            if (ixj > t) {
                float ka = key[t], kb = key[ixj];
                int   ia = idx[t], ib = idx[ixj];
                bool up = ((t & k2) == 0);
                bool a_before_b = (ka > kb) || (ka == kb && ia < ib);
                bool do_swap = up ? !a_before_b : a_before_b;
                if (do_swap) { key[t] = kb; key[ixj] = ka; idx[t] = ib; idx[ixj] = ia; }
            }
        }
    }
    __syncthreads();
    int el = idx[t];
    int eg = ebase + el;
    float pv = key[t];
    float r = (float)ei[eg];
    float c = (float)ei[E_ + eg];
    float av = ea[eg];
    if (t < KSEL) {
        int oo = g * KSEL + t;
        out[OFF1 + oo]      = r;
        out[OFF1 + GK + oo] = c;
        out[OFF2 + oo]      = av;
        out[OFF3 + oo]      = pv;
    } else {
        int oo = g * KSEL + (t - KSEL);
        out[OFF6 + oo]      = r;
        out[OFF6 + GK + oo] = c;
        out[OFF7 + oo]      = av;
        out[OFF8 + oo]      = -pv;
    }
    out[OFF10 + ebase + t] = p;
}

__global__ void k_batch(const int* __restrict__ batch, float* __restrict__ out) {
    int i = blockIdx.x * 256 + threadIdx.x;
    if (i < N_) { float b = (float)batch[i]; out[OFF4 + i] = b; out[OFF9 + i] = b; }
}

extern "C" void kernel_launch(void* const* d_in, const int* in_sizes, int n_in,
                              void* d_out, int out_size, void* d_ws, size_t ws_size,
                              hipStream_t stream) {
    const float* x     = (const float*)d_in[0];
    const int*   ei    = (const int*)  d_in[1];
    const float* ea    = (const float*)d_in[2];
    const int*   batch = (const int*)  d_in[3];
    const float* W1    = (const float*)d_in[4];
    const float* V1    = (const float*)d_in[5];
    const float* b1    = (const float*)d_in[6];
    const float* W2    = (const float*)d_in[7];
    const float* V2    = (const float*)d_in[8];
    const float* b2    = (const float*)d_in[9];
    const float* mw1   = (const float*)d_in[10];
    const float* mb1   = (const float*)d_in[11];
    const float* mw2   = (const float*)d_in[12];
    const float* mb2   = (const float*)d_in[13];
    float* out = (float*)d_out;

    char* ws = (char*)d_ws;
    size_t o = 0;
    float* deg  = (float*)(ws + o); o += (size_t)N_ * 4;          // 256 KB
    float* norm = (float*)(ws + o); o += (size_t)E_ * 4;          // 1 MB
    float* pred = (float*)(ws + o); o += (size_t)E_ * 4;          // 1 MB
    u16* WV1t   = (u16*)(ws + o);   o += (size_t)256 * IN_CH * 2; // 384 KB
    u16* WV2t   = (u16*)(ws + o);   o += (size_t)256 * CH * 2;    // 64 KB
    u16* Mwt    = (u16*)(ws + o);   o += (size_t)1024 * CH * 2;   // 256 KB
    u16* x2b    = (u16*)(ws + o);   o += (size_t)N_ * CH * 2;     // 16 MB
    u16* x1b    = (u16*)(ws + o);   o += (size_t)N_ * CH * 2;     // 16 MB
    u16* B1b    = (u16*)(ws + o);   o += (size_t)N_ * 256 * 2;    // 32 MB

    // degree / norm / weights
    hipMemsetAsync(deg, 0, (size_t)N_ * 4, stream);
    k_deg <<<E_/256, 256, 0, stream>>>(ei, ea, deg);
    k_dis <<<N_/256, 256, 0, stream>>>(deg);
    k_norm<<<E_/256, 256, 0, stream>>>(ei, ea, deg, norm);
    k_concat<<<768, 256, 0, stream>>>(W1, V1, W2, V2, mw1, WV1t, WV2t, Mwt);

    // layer 1: B1b = bf16([m|v]) = x @ [W1|V1]  (linear full-K panel stage)
    k_gemm1<<<N_/16, 256, 0, stream>>>(x, WV1t, B1b);
    k_agg1<<<G_, 256, 0, stream>>>(ei, norm, B1b, b1, x1b);
    // layer 2 fused: per-graph GEMM + aggregation -> x2 (both slots) + x2b
    k_l2agg<<<G_, 256, 0, stream>>>(x1b, WV2t, ei, norm, b2, out + OFF0, out + OFF5, x2b);
    // fused edge MLP
    k_pqedge<<<G_, 512, 0, stream>>>(x2b, Mwt, ei, mb1, mw2, mb2, pred);
    // per-graph top-K partition + outputs
    k_sort<<<G_, 256, 0, stream>>>(pred, ei, ea, out);
    k_batch<<<N_/256, 256, 0, stream>>>(batch, out);
}

// Round 13
// 229.367 us; speedup vs baseline: 1.5441x; 1.5441x over previous
//
#include <hip/hip_runtime.h>
#include <hip/hip_bf16.h>
#include <stdint.h>

#define G_    1024
#define NPG   64
#define EPG   256
#define N_    (G_*NPG)     // 65536
#define E_    (G_*EPG)     // 262144
#define IN_CH 768
#define CH    128
#define KSEL  128
#define HID   512          // 4*CH

// ---- output layout (element offsets, all float32) ----
#define NCH  (N_*CH)       // 8388608
#define GK   (G_*KSEL)     // 131072
#define OFF0 0
#define OFF1 (OFF0 + NCH)
#define OFF2 (OFF1 + 2*GK)
#define OFF3 (OFF2 + GK)
#define OFF4 (OFF3 + GK)
#define OFF5 (OFF4 + N_)
#define OFF6 (OFF5 + NCH)
#define OFF7 (OFF6 + 2*GK)
#define OFF8 (OFF7 + GK)
#define OFF9 (OFF8 + GK)
#define OFF10 (OFF9 + N_)

typedef unsigned short u16;
typedef unsigned int   u32;
typedef __attribute__((ext_vector_type(8))) short bf16x8;
typedef __attribute__((ext_vector_type(4))) float f32x4;

__device__ __forceinline__ u16 f2bf(float x) {
    union { float f; u32 u; } v; v.f = x;
    u32 r = v.u + 0x7fffu + ((v.u >> 16) & 1u);   // RNE
    return (u16)(r >> 16);
}
__device__ __forceinline__ float bf2f(u32 h) {
    union { u32 u; float f; } v; v.u = h << 16; return v.f;
}
__device__ __forceinline__ u16 bfc(float x) {
    __hip_bfloat16 h = __float2bfloat16(x);
    return *reinterpret_cast<u16*>(&h);
}

__global__ void k_deg(const int* __restrict__ ei, const float* __restrict__ ea,
                      float* __restrict__ deg) {
    int e = blockIdx.x * 256 + threadIdx.x;
    if (e < E_) atomicAdd(&deg[ei[E_ + e]], ea[e]);
}

// fused dis+norm: norm[e] = dis(deg[row]) * ea * dis(deg[col])
__global__ void k_norm(const int* __restrict__ ei, const float* __restrict__ ea,
                       const float* __restrict__ deg, float* __restrict__ norm) {
    int e = blockIdx.x * 256 + threadIdx.x;
    if (e >= E_) return;
    float dr = deg[ei[e]], dc = deg[ei[E_ + e]];
    float fr = dr > 0.f ? 1.0f / sqrtf(dr) : 0.f;
    float fc = dc > 0.f ? 1.0f / sqrtf(dc) : 0.f;
    norm[e] = fr * ea[e] * fc;
}

// Build TRANSPOSED bf16 weights (row = output col, cols = K).
__global__ void k_concat(const float* __restrict__ W1, const float* __restrict__ V1,
                         const float* __restrict__ W2, const float* __restrict__ V2,
                         const float* __restrict__ mw1,
                         u16* __restrict__ WV1t, u16* __restrict__ WV2t,
                         u16* __restrict__ Mwt) {
    int i = blockIdx.x * 256 + threadIdx.x;
    if (i < 256 * IN_CH) {
        int c = i / IN_CH, r = i - c * IN_CH;
        WV1t[i] = f2bf(c < CH ? W1[r*CH + c] : V1[r*CH + (c - CH)]);
    }
    if (i < 256 * CH) {
        int c = i >> 7, r = i & 127;
        WV2t[i] = f2bf(c < CH ? W2[r*CH + c] : V2[r*CH + (c - CH)]);
    }
    if (i < 1024 * CH) {
        int c = i >> 7, r = i & 127;
        Mwt[i] = f2bf(c < HID ? mw1[r*HID + c] : mw1[(CH + r)*HID + (c - HID)]);
    }
}

// Layer-1 GEMM (round-7 version verbatim, 124 us): C(N x 256 bf16) =
// bf16(x(N x 768 f32)) @ WV1t^T.  BM=128, grid.y=2, global_load_lds(16B),
// 2-buffer, XOR-swizzled source + swizzled ds_read.
__global__ __launch_bounds__(256) void k_gemm1(const float* __restrict__ Ap,
        const u16* __restrict__ Bt, u16* __restrict__ Cp) {
    __shared__ float As[2][128 * 32];     // 2 x 16 KB
    const int t = threadIdx.x;
    const int lane = t & 63, w = t >> 6;
    const int wr = (w >> 1) << 6, wc = (w & 1) << 6;
    const size_t bm = (size_t)blockIdx.x * 128;
    const size_t bn = (size_t)blockIdx.y * 128;
    const int r16 = lane & 15, kq = lane >> 4;

    int cid[4], grow[4], gcol[4];
    #pragma unroll
    for (int i = 0; i < 4; ++i) {
        int c = i * 256 + t;
        cid[i] = c;
        int row = c >> 3, sl = c & 7;
        grow[i] = row;
        gcol[i] = (sl ^ (row & 7)) * 4;
    }

    f32x4 acc[4][4];
    #pragma unroll
    for (int m = 0; m < 4; ++m)
        #pragma unroll
        for (int n = 0; n < 4; ++n)
            acc[m][n] = (f32x4){0.f, 0.f, 0.f, 0.f};

    #define STAGE(buf, k0)                                                      \
        do {                                                                    \
            _Pragma("unroll")                                                   \
            for (int i = 0; i < 4; ++i) {                                       \
                const float* src = Ap + (bm + grow[i]) * (size_t)IN_CH + (k0) + gcol[i]; \
                __builtin_amdgcn_global_load_lds(                               \
                    (const __attribute__((address_space(1))) void*)src,         \
                    (__attribute__((address_space(3))) void*)&As[buf][cid[i] * 4], \
                    16, 0, 0);                                                  \
            }                                                                   \
        } while (0)

    #define LOADB(bv, k0)                                                       \
        do {                                                                    \
            _Pragma("unroll")                                                   \
            for (int n = 0; n < 4; ++n)                                         \
                bv[n] = *(const bf16x8*)(Bt + (bn + wc + n * 16 + r16) * (size_t)IN_CH + (k0) + kq * 8); \
        } while (0)

    STAGE(0, 0);
    bf16x8 bc[4];
    LOADB(bc, 0);
    __syncthreads();

    const int nk = IN_CH / 32;     // 24
    int buf = 0;
    for (int ki = 0; ki < nk; ++ki) {
        bf16x8 bnx[4];
        if (ki + 1 < nk) {
            STAGE(buf ^ 1, (ki + 1) * 32);
            LOADB(bnx, (ki + 1) * 32);
        }
        bf16x8 a[4];
        #pragma unroll
        for (int m = 0; m < 4; ++m) {
            int row = wr + m * 16 + r16;
            int xr = row & 7;
            const float* base = &As[buf][row * 32];
            float4 q0 = *(const float4*)(base + (((2 * kq)     ^ xr) * 4));
            float4 q1 = *(const float4*)(base + (((2 * kq + 1) ^ xr) * 4));
            union { bf16x8 v; u16 s[8]; } pk;
            pk.s[0] = bfc(q0.x); pk.s[1] = bfc(q0.y); pk.s[2] = bfc(q0.z); pk.s[3] = bfc(q0.w);
            pk.s[4] = bfc(q1.x); pk.s[5] = bfc(q1.y); pk.s[6] = bfc(q1.z); pk.s[7] = bfc(q1.w);
            a[m] = pk.v;
        }
        #pragma unroll
        for (int m = 0; m < 4; ++m)
            #pragma unroll
            for (int n = 0; n < 4; ++n)
                acc[m][n] = __builtin_amdgcn_mfma_f32_16x16x32_bf16(a[m], bc[n], acc[m][n], 0, 0, 0);
        if (ki + 1 < nk) {
            #pragma unroll
            for (int n = 0; n < 4; ++n) bc[n] = bnx[n];
        }
        __syncthreads();
        buf ^= 1;
    }
    #undef STAGE
    #undef LOADB

    #pragma unroll
    for (int m = 0; m < 4; ++m)
        #pragma unroll
        for (int j = 0; j < 4; ++j) {
            size_t row = bm + wr + m * 16 + kq * 4 + j;
            #pragma unroll
            for (int n = 0; n < 4; ++n) {
                size_t col = bn + wc + n * 16 + r16;
                Cp[row * 256 + col] = f2bf(acc[m][n][j]);
            }
        }
}

// ======================= fused per-graph mega-kernel =======================
// Per graph g (1024 blocks x 512 thr): adjacency (built once) -> agg1 ->
// layer-2 GEMM -> agg2 (-> out0/out5) -> PQ GEMM -> edge MLP -> top-K sort
// -> all remaining outputs. x1/x2/PQ/pred never leave LDS.
// LDS overlay (bytes):
//   [0,16640)        A_s   f32[64*65]        (phases 1-4)
//   [16640,34048)    Ms    u16[64][136]      (phase 2)
//   [34048,51456)    x1s   u16[64][136]      (phases 2-3)
//   [51456,86272)    MVs   u16[64][272]      (phases 3-4)
//   [0,132096)       PQs   u16[64][1032]     (phases 5-6; overlays the above)
//   [0,1024)/[1024,2048)  key/idx            (phase 7; overlays PQs)
//   [132096,134144)  mw2s  f32[512]
//   [134144,151552)  x2s   u16[64][136]      (phases 4-5)
//   [151552,152576)  predv f32[256]          (phases 6-7)
#define PQS 1032
__global__ __launch_bounds__(512) void k_graph(const u16* __restrict__ B1b,
        const u16* __restrict__ WV2t, const u16* __restrict__ Mwt,
        const int* __restrict__ ei, const float* __restrict__ norm,
        const float* __restrict__ b1, const float* __restrict__ b2,
        const float* __restrict__ mb1, const float* __restrict__ mw2,
        const float* __restrict__ mb2, const float* __restrict__ ea,
        float* __restrict__ out) {
    __shared__ char Lds[152576];
    float* A_s   = (float*)(Lds + 0);
    u16*   Ms    = (u16*)(Lds + 16640);
    u16*   x1s   = (u16*)(Lds + 34048);
    u16*   MVs   = (u16*)(Lds + 51456);
    u16*   PQs   = (u16*)(Lds + 0);
    float* mw2s  = (float*)(Lds + 132096);
    u16*   x2s   = (u16*)(Lds + 134144);
    float* predv = (float*)(Lds + 151552);
    float* key   = (float*)(Lds + 0);
    int*   idx   = (int*)(Lds + 1024);

    const int g = blockIdx.x, t = threadIdx.x;
    const int lane = t & 63, w = t >> 6;          // 8 waves
    const int r16 = lane & 15, kq = lane >> 4;
    const size_t nbase = (size_t)g * 64;
    union bfr { bf16x8 v; u16 s[8]; };

    // ---- phase 1: stage mw2, zero A_s, stage Ms (m-cols of B1b), edges ----
    if (t < 128) *(float4*)&mw2s[t * 4] = *(const float4*)&mw2[t * 4];
    for (int i = t; i < 64 * 65; i += 512) A_s[i] = 0.f;
    for (int i = t; i < 64 * 32; i += 512) {
        int row = i >> 5, c4 = (i & 31) << 2;
        *(uint2*)&Ms[row * 136 + c4] = *(const uint2*)(B1b + (nbase + row) * 256 + c4);
    }
    int er = 0, ec = 0; float env = 0.f;
    if (t < 256) { int e = g * 256 + t; er = ei[e] & 63; ec = ei[E_ + e] & 63; env = norm[e]; }
    __syncthreads();
    if (t < 256) atomicAdd(&A_s[er * 65 + ec], env);
    __syncthreads();

    // ---- phase 2: agg1 -> x1s = bf16(relu(A^T m + v + b1)) ----
    {
        const int n0 = w * 16;
        f32x4 acc[4];
        #pragma unroll
        for (int mt = 0; mt < 4; ++mt) acc[mt] = (f32x4){0.f, 0.f, 0.f, 0.f};
        #pragma unroll
        for (int ks = 0; ks < 2; ++ks) {
            bfr a[4], b;
            #pragma unroll
            for (int mt = 0; mt < 4; ++mt)
                #pragma unroll
                for (int i = 0; i < 8; ++i)
                    a[mt].s[i] = f2bf(A_s[(ks*32 + kq*8 + i) * 65 + mt*16 + r16]);
            #pragma unroll
            for (int i = 0; i < 8; ++i)
                b.s[i] = Ms[(ks*32 + kq*8 + i) * 136 + n0 + r16];
            #pragma unroll
            for (int mt = 0; mt < 4; ++mt)
                acc[mt] = __builtin_amdgcn_mfma_f32_16x16x32_bf16(a[mt].v, b.v, acc[mt], 0, 0, 0);
        }
        const int ch = w * 16 + r16;
        #pragma unroll
        for (int mt = 0; mt < 4; ++mt)
            #pragma unroll
            for (int j = 0; j < 4; ++j) {
                int c = mt * 16 + kq * 4 + j;
                float v = bf2f(B1b[(nbase + c) * 256 + 128 + ch]) + b1[ch];
                x1s[c * 136 + ch] = f2bf(fmaxf(acc[mt][j] + v, 0.f));
            }
    }
    __syncthreads();

    // ---- phase 3: layer-2 GEMM  MVs = x1 @ WV2t^T (8 waves x 32 cols) ----
    {
        const int wc2 = w * 32;
        f32x4 acc[4][2];
        #pragma unroll
        for (int mt = 0; mt < 4; ++mt)
            #pragma unroll
            for (int n = 0; n < 2; ++n) acc[mt][n] = (f32x4){0.f, 0.f, 0.f, 0.f};
        #pragma unroll
        for (int ks = 0; ks < 4; ++ks) {
            bf16x8 a[4], b[2];
            #pragma unroll
            for (int mt = 0; mt < 4; ++mt)
                a[mt] = *(const bf16x8*)&x1s[(mt*16 + r16) * 136 + ks*32 + kq*8];
            #pragma unroll
            for (int n = 0; n < 2; ++n)
                b[n] = *(const bf16x8*)(WV2t + (size_t)(wc2 + n*16 + r16) * 128 + ks*32 + kq*8);
            #pragma unroll
            for (int mt = 0; mt < 4; ++mt)
                #pragma unroll
                for (int n = 0; n < 2; ++n)
                    acc[mt][n] = __builtin_amdgcn_mfma_f32_16x16x32_bf16(a[mt], b[n], acc[mt][n], 0, 0, 0);
        }
        #pragma unroll
        for (int mt = 0; mt < 4; ++mt)
            #pragma unroll
            for (int j = 0; j < 4; ++j) {
                int row = mt * 16 + kq * 4 + j;
                #pragma unroll
                for (int n = 0; n < 2; ++n)
                    MVs[row * 272 + wc2 + n*16 + r16] = f2bf(acc[mt][n][j]);
            }
    }
    __syncthreads();

    // ---- phase 4: agg2 -> out0/out5 + x2s ----
    {
        const int n0 = w * 16;
        f32x4 acc[4];
        #pragma unroll
        for (int mt = 0; mt < 4; ++mt) acc[mt] = (f32x4){0.f, 0.f, 0.f, 0.f};
        #pragma unroll
        for (int ks = 0; ks < 2; ++ks) {
            bfr a[4], b;
            #pragma unroll
            for (int mt = 0; mt < 4; ++mt)
                #pragma unroll
                for (int i = 0; i < 8; ++i)
                    a[mt].s[i] = f2bf(A_s[(ks*32 + kq*8 + i) * 65 + mt*16 + r16]);
            #pragma unroll
            for (int i = 0; i < 8; ++i)
                b.s[i] = MVs[(ks*32 + kq*8 + i) * 272 + n0 + r16];
            #pragma unroll
            for (int mt = 0; mt < 4; ++mt)
                acc[mt] = __builtin_amdgcn_mfma_f32_16x16x32_bf16(a[mt].v, b.v, acc[mt], 0, 0, 0);
        }
        const int ch = w * 16 + r16;
        #pragma unroll
        for (int mt = 0; mt < 4; ++mt)
            #pragma unroll
            for (int j = 0; j < 4; ++j) {
                int c = mt * 16 + kq * 4 + j;
                float v = bf2f(MVs[c * 272 + 128 + ch]) + b2[ch];
                float r = fmaxf(acc[mt][j] + v, 0.f);
                size_t node = nbase + c;
                out[OFF0 + node * 128 + ch] = r;
                out[OFF5 + node * 128 + ch] = r;
                x2s[c * 136 + ch] = f2bf(r);
            }
    }
    __syncthreads();

    // ---- phase 5: PQ GEMM -> PQs (mb1 folded into P cols) ----
    {
        const int nb = w * 128;
        f32x4 acc[4][8];
        #pragma unroll
        for (int mt = 0; mt < 4; ++mt)
            #pragma unroll
            for (int nt = 0; nt < 8; ++nt) acc[mt][nt] = (f32x4){0.f, 0.f, 0.f, 0.f};
        #pragma unroll
        for (int ks = 0; ks < 4; ++ks) {
            bf16x8 a[4], b[8];
            #pragma unroll
            for (int mt = 0; mt < 4; ++mt)
                a[mt] = *(const bf16x8*)&x2s[(mt*16 + r16) * 136 + ks*32 + kq*8];
            #pragma unroll
            for (int nt = 0; nt < 8; ++nt)
                b[nt] = *(const bf16x8*)(Mwt + (size_t)(nb + nt*16 + r16) * 128 + ks*32 + kq*8);
            #pragma unroll
            for (int mt = 0; mt < 4; ++mt)
                #pragma unroll
                for (int nt = 0; nt < 8; ++nt)
                    acc[mt][nt] = __builtin_amdgcn_mfma_f32_16x16x32_bf16(a[mt], b[nt], acc[mt][nt], 0, 0, 0);
        }
        #pragma unroll
        for (int nt = 0; nt < 8; ++nt) {
            int col = nb + nt * 16 + r16;
            float bias = (col < HID) ? mb1[col] : 0.f;
            #pragma unroll
            for (int mt = 0; mt < 4; ++mt)
                #pragma unroll
                for (int j = 0; j < 4; ++j) {
                    int row = mt * 16 + kq * 4 + j;
                    PQs[row * PQS + col] = f2bf(acc[mt][nt][j] + bias);
                }
        }
    }
    __syncthreads();

    // ---- phase 6: edge combine -> predv + OFF10 ----
    {
        const int le = lane & 31, jh = lane >> 5;
        const int eloc = w * 32 + le;
        const int e = g * 256 + eloc;
        const int r = ei[e] & 63, c = ei[E_ + e] & 63;
        const u16* pP = &PQs[r * PQS + jh * 256];
        const u16* pQ = &PQs[c * PQS + 512 + jh * 256];
        const float* pW = &mw2s[jh * 256];
        float s = 0.f;
        #pragma unroll 8
        for (int it = 0; it < 32; ++it) {
            uint4 up = *(const uint4*)(pP + it * 8);
            uint4 uq = *(const uint4*)(pQ + it * 8);
            float4 w0 = *(const float4*)(pW + it * 8);
            float4 w1 = *(const float4*)(pW + it * 8 + 4);
            u32 pu[4] = {up.x, up.y, up.z, up.w};
            u32 qu[4] = {uq.x, uq.y, uq.z, uq.w};
            float ww[8] = {w0.x,w0.y,w0.z,w0.w,w1.x,w1.y,w1.z,w1.w};
            #pragma unroll
            for (int k = 0; k < 4; ++k) {
                float p0 = bf2f(pu[k] & 0xffffu), p1 = bf2f(pu[k] >> 16);
                float q0 = bf2f(qu[k] & 0xffffu), q1 = bf2f(qu[k] >> 16);
                s += fmaxf(p0 + q0, 0.f) * ww[2*k];
                s += fmaxf(p1 + q1, 0.f) * ww[2*k + 1];
            }
        }
        s += __shfl_xor(s, 32, 64);
        if (lane < 32) {
            float pv = s + mb2[0];
            predv[eloc] = pv;
            out[OFF10 + e] = pv;
        }
    }
    __syncthreads();

    // ---- phase 7: stable bitonic top-K sort + remaining outputs ----
    if (t < 256) { key[t] = predv[t]; idx[t] = t; }
    for (int k2 = 2; k2 <= 256; k2 <<= 1) {
        for (int j = k2 >> 1; j >= 1; j >>= 1) {
            __syncthreads();
            if (t < 256) {
                int ixj = t ^ j;
                if (ixj > t) {
                    float ka = key[t], kb = key[ixj];
                    int   ia = idx[t], ib = idx[ixj];
                    bool up = ((t & k2) == 0);
                    bool a_before_b = (ka > kb) || (ka == kb && ia < ib);
                    bool do_swap = up ? !a_before_b : a_before_b;
                    if (do_swap) { key[t] = kb; key[ixj] = ka; idx[t] = ib; idx[ixj] = ia; }
                }
            }
        }
    }
    __syncthreads();
    if (t < 256) {
        int el = idx[t];
        int eg = g * 256 + el;
        float pv = key[t];
        float r = (float)ei[eg];
        float c = (float)ei[E_ + eg];
        float av = ea[eg];
        if (t < KSEL) {
            int oo = g * KSEL + t;
            out[OFF1 + oo]      = r;
            out[OFF1 + GK + oo] = c;
            out[OFF2 + oo]      = av;
            out[OFF3 + oo]      = pv;
        } else {
            int oo = g * KSEL + (t - KSEL);
            out[OFF6 + oo]      = r;
            out[OFF6 + GK + oo] = c;
            out[OFF7 + oo]      = av;
            out[OFF8 + oo]      = -pv;
        }
    }
    if (t < 64) {
        out[OFF4 + nbase + t] = (float)g;   // batch[node] == g
        out[OFF9 + nbase + t] = (float)g;
    }
}

extern "C" void kernel_launch(void* const* d_in, const int* in_sizes, int n_in,
                              void* d_out, int out_size, void* d_ws, size_t ws_size,
                              hipStream_t stream) {
    const float* x     = (const float*)d_in[0];
    const int*   ei    = (const int*)  d_in[1];
    const float* ea    = (const float*)d_in[2];
    const float* W1    = (const float*)d_in[4];
    const float* V1    = (const float*)d_in[5];
    const float* b1    = (const float*)d_in[6];
    const float* W2    = (const float*)d_in[7];
    const float* V2    = (const float*)d_in[8];
    const float* b2    = (const float*)d_in[9];
    const float* mw1   = (const float*)d_in[10];
    const float* mb1   = (const float*)d_in[11];
    const float* mw2   = (const float*)d_in[12];
    const float* mb2   = (const float*)d_in[13];
    float* out = (float*)d_out;

    char* ws = (char*)d_ws;
    size_t o = 0;
    float* deg  = (float*)(ws + o); o += (size_t)N_ * 4;          // 256 KB
    float* norm = (float*)(ws + o); o += (size_t)E_ * 4;          // 1 MB
    u16* WV1t   = (u16*)(ws + o);   o += (size_t)256 * IN_CH * 2; // 384 KB
    u16* WV2t   = (u16*)(ws + o);   o += (size_t)256 * CH * 2;    // 64 KB
    u16* Mwt    = (u16*)(ws + o);   o += (size_t)1024 * CH * 2;   // 256 KB
    u16* B1b    = (u16*)(ws + o);   o += (size_t)N_ * 256 * 2;    // 32 MB

    // prep: degree, fused dis+norm, transposed bf16 weights
    hipMemsetAsync(deg, 0, (size_t)N_ * 4, stream);
    k_deg <<<E_/256, 256, 0, stream>>>(ei, ea, deg);
    k_norm<<<E_/256, 256, 0, stream>>>(ei, ea, deg, norm);
    k_concat<<<768, 256, 0, stream>>>(W1, V1, W2, V2, mw1, WV1t, WV2t, Mwt);

    // layer 1 GEMM: B1b = bf16([m|v]) = x @ [W1|V1]
    dim3 g1(N_/128, 2);
    k_gemm1<<<g1, 256, 0, stream>>>(x, WV1t, B1b);

    // everything else fused per-graph
    k_graph<<<G_, 512, 0, stream>>>(B1b, WV2t, Mwt, ei, norm, b1, b2,
                                    mb1, mw2, mb2, ea, out);
}